// Round 2
// baseline (2968.457 us; speedup 1.0000x reference)
//
#include <hip/hip_runtime.h>

// MultiheadAttn forward, fp32. T=2048, B=2, E=1024, H=16, hd=64.
// d_out = out[T,B,E] (4M floats) ++ avg_weights[B,T,T] (8M floats).
// ws layout: q[32][2048][64] | k[...] | v[...] | ctx[T,B,E]  = 64 MB fp32.

#define T_DIM 2048
#define B_DIM 2
#define E_DIM 1024
#define H_DIM 16
#define HD 64
#define F_DIM 3072
#define M_DIM (T_DIM * B_DIM)
#define SCALE 0.125f  // hd^-0.5

// ---------------------------------------------------------------------------
// GEMM (NT): C[r,f] = sum_e A[r,e] * W[f,e] + bias[f]
// MODE 0: split-store into q/k/v head-major [n=b*H+h][t][d], q scaled.
// MODE 1: plain store out[r*E + f].
// BM=BN=64, BK=16, 256 threads, 4x4 per thread.
// ---------------------------------------------------------------------------
template <int MODE>
__global__ __launch_bounds__(256) void gemm_nt(
    const float* __restrict__ A, const float* __restrict__ W,
    const float* __restrict__ bias,
    float* __restrict__ qb, float* __restrict__ kb, float* __restrict__ vb,
    float* __restrict__ outp)
{
    __shared__ float As[16][68];  // [k][m], pad->68 keeps f4 reads aligned
    __shared__ float Bs[16][68];  // [k][n]

    const int tid = threadIdx.x;
    const int tx = tid & 15, ty = tid >> 4;
    const int n0 = blockIdx.x * 64, m0 = blockIdx.y * 64;
    const int lrow = tid >> 2, lc4 = tid & 3;

    float acc[4][4] = {};

    for (int k0 = 0; k0 < E_DIM; k0 += 16) {
        __syncthreads();
        float4 av = *(const float4*)&A[(size_t)(m0 + lrow) * E_DIM + k0 + lc4 * 4];
        float4 bv = *(const float4*)&W[(size_t)(n0 + lrow) * E_DIM + k0 + lc4 * 4];
        As[lc4 * 4 + 0][lrow] = av.x; As[lc4 * 4 + 1][lrow] = av.y;
        As[lc4 * 4 + 2][lrow] = av.z; As[lc4 * 4 + 3][lrow] = av.w;
        Bs[lc4 * 4 + 0][lrow] = bv.x; Bs[lc4 * 4 + 1][lrow] = bv.y;
        Bs[lc4 * 4 + 2][lrow] = bv.z; Bs[lc4 * 4 + 3][lrow] = bv.w;
        __syncthreads();
#pragma unroll
        for (int kk = 0; kk < 16; ++kk) {
            float4 a4 = *(const float4*)&As[kk][ty * 4];
            float4 b4 = *(const float4*)&Bs[kk][tx * 4];
            float am[4] = {a4.x, a4.y, a4.z, a4.w};
            float bn[4] = {b4.x, b4.y, b4.z, b4.w};
#pragma unroll
            for (int i = 0; i < 4; ++i)
#pragma unroll
                for (int j = 0; j < 4; ++j)
                    acc[i][j] += am[i] * bn[j];
        }
    }

#pragma unroll
    for (int i = 0; i < 4; ++i) {
        const int r = m0 + ty * 4 + i;
        const int t = r >> 1, b = r & 1;
#pragma unroll
        for (int j = 0; j < 4; ++j) {
            const int f = n0 + tx * 4 + j;
            float val = acc[i][j] + bias[f];
            if (MODE == 0) {
                const int sec = f >> 10;
                const int rem = f & 1023;
                const int h = rem >> 6, d = rem & 63;
                const size_t idx = ((size_t)(b * H_DIM + h) * T_DIM + t) * HD + d;
                if (sec == 0)      qb[idx] = val * SCALE;
                else if (sec == 1) kb[idx] = val;
                else               vb[idx] = val;
            } else {
                outp[(size_t)r * E_DIM + f] = val;
            }
        }
    }
}

// ---------------------------------------------------------------------------
// Attention: one block per (head n, 32-query tile). 256 threads = 4 waves.
// Phase 1: online-softmax stats (m,l) per row, wave-local (wave w owns
//          q === w mod 4; the 64 lanes hold the 64 keys of each K-tile).
// Phase 2: recompute scores, p=exp(s-m)/l, atomicAdd p/H into avg,
//          accumulate PV via LDS P-tile.
// ---------------------------------------------------------------------------
__global__ __launch_bounds__(256) void attn_kernel(
    const float* __restrict__ qbuf, const float* __restrict__ kbuf,
    const float* __restrict__ vbuf, float* __restrict__ ctx,
    float* __restrict__ avg)
{
    __shared__ float Qs[32][64];
    __shared__ float Ks[64][65];
    __shared__ float Vs[64][65];
    __shared__ float Ps[32][64];

    const int tid = threadIdx.x;
    const int lane = tid & 63;
    const int w = tid >> 6;           // wave id 0..3
    const int q0 = blockIdx.x * 32;
    const int n = blockIdx.y;         // head index b*H+h
    const int b = n >> 4, h = n & 15;

    const float* qh = qbuf + (size_t)n * T_DIM * HD;
    const float* kh = kbuf + (size_t)n * T_DIM * HD;
    const float* vh = vbuf + (size_t)n * T_DIM * HD;

    // load 32x64 Q tile
#pragma unroll
    for (int i = 0; i < 2; ++i) {
        int pos = tid + i * 256;
        int row = pos >> 4, c4 = pos & 15;
        *(float4*)&Qs[row][c4 * 4] = *(const float4*)&qh[(size_t)(q0 + row) * HD + c4 * 4];
    }

    float m[8], l[8];
#pragma unroll
    for (int i = 0; i < 8; ++i) { m[i] = -1e30f; l[i] = 0.f; }

    // ---- phase 1: stats ----
    for (int kt = 0; kt < T_DIM; kt += 64) {
        __syncthreads();
#pragma unroll
        for (int i = 0; i < 4; ++i) {
            int pos = tid + i * 256;
            int row = pos >> 4, c4 = pos & 15;
            float4 kv = *(const float4*)&kh[(size_t)(kt + row) * HD + c4 * 4];
            Ks[row][c4 * 4 + 0] = kv.x; Ks[row][c4 * 4 + 1] = kv.y;
            Ks[row][c4 * 4 + 2] = kv.z; Ks[row][c4 * 4 + 3] = kv.w;
        }
        __syncthreads();

        float s[8] = {0.f, 0.f, 0.f, 0.f, 0.f, 0.f, 0.f, 0.f};
#pragma unroll
        for (int e4 = 0; e4 < 16; ++e4) {
            float k0v = Ks[lane][e4 * 4 + 0];
            float k1v = Ks[lane][e4 * 4 + 1];
            float k2v = Ks[lane][e4 * 4 + 2];
            float k3v = Ks[lane][e4 * 4 + 3];
#pragma unroll
            for (int i = 0; i < 8; ++i) {
                float4 qv = *(const float4*)&Qs[w + 4 * i][e4 * 4];
                s[i] += qv.x * k0v + qv.y * k1v + qv.z * k2v + qv.w * k3v;
            }
        }
#pragma unroll
        for (int i = 0; i < 8; ++i) {
            float mt = s[i];
#pragma unroll
            for (int off = 32; off >= 1; off >>= 1)
                mt = fmaxf(mt, __shfl_xor(mt, off));
            float m_new = fmaxf(m[i], mt);
            float pe = __expf(s[i] - m_new);
            float lt = pe;
#pragma unroll
            for (int off = 32; off >= 1; off >>= 1)
                lt += __shfl_xor(lt, off);
            l[i] = l[i] * __expf(m[i] - m_new) + lt;
            m[i] = m_new;
        }
    }

    float linv[8];
#pragma unroll
    for (int i = 0; i < 8; ++i) linv[i] = 1.0f / l[i];

    float acc[8] = {};

    // ---- phase 2: emit ----
    for (int kt = 0; kt < T_DIM; kt += 64) {
        __syncthreads();
#pragma unroll
        for (int i = 0; i < 4; ++i) {
            int pos = tid + i * 256;
            int row = pos >> 4, c4 = pos & 15;
            float4 kv = *(const float4*)&kh[(size_t)(kt + row) * HD + c4 * 4];
            float4 vv = *(const float4*)&vh[(size_t)(kt + row) * HD + c4 * 4];
            Ks[row][c4 * 4 + 0] = kv.x; Ks[row][c4 * 4 + 1] = kv.y;
            Ks[row][c4 * 4 + 2] = kv.z; Ks[row][c4 * 4 + 3] = kv.w;
            Vs[row][c4 * 4 + 0] = vv.x; Vs[row][c4 * 4 + 1] = vv.y;
            Vs[row][c4 * 4 + 2] = vv.z; Vs[row][c4 * 4 + 3] = vv.w;
        }
        __syncthreads();

        float s[8] = {0.f, 0.f, 0.f, 0.f, 0.f, 0.f, 0.f, 0.f};
#pragma unroll
        for (int e4 = 0; e4 < 16; ++e4) {
            float k0v = Ks[lane][e4 * 4 + 0];
            float k1v = Ks[lane][e4 * 4 + 1];
            float k2v = Ks[lane][e4 * 4 + 2];
            float k3v = Ks[lane][e4 * 4 + 3];
#pragma unroll
            for (int i = 0; i < 8; ++i) {
                float4 qv = *(const float4*)&Qs[w + 4 * i][e4 * 4];
                s[i] += qv.x * k0v + qv.y * k1v + qv.z * k2v + qv.w * k3v;
            }
        }
#pragma unroll
        for (int i = 0; i < 8; ++i) {
            float p = __expf(s[i] - m[i]) * linv[i];
            Ps[w + 4 * i][lane] = p;
            atomicAdd(&avg[((size_t)b * T_DIM + q0 + w + 4 * i) * T_DIM + kt + lane],
                      p * (1.0f / H_DIM));
        }
        __syncthreads();

        // PV: acc[q][d=lane] += sum_kk Ps[q][kk] * Vs[kk][lane]
#pragma unroll
        for (int kk4 = 0; kk4 < 64; kk4 += 4) {
            float v0 = Vs[kk4 + 0][lane];
            float v1 = Vs[kk4 + 1][lane];
            float v2 = Vs[kk4 + 2][lane];
            float v3 = Vs[kk4 + 3][lane];
#pragma unroll
            for (int i = 0; i < 8; ++i) {
                float4 pq = *(const float4*)&Ps[w + 4 * i][kk4];
                acc[i] += pq.x * v0 + pq.y * v1 + pq.z * v2 + pq.w * v3;
            }
        }
    }

    // store context: ctx[(t*B + b)*E + h*64 + d]
#pragma unroll
    for (int i = 0; i < 8; ++i) {
        ctx[((size_t)(q0 + w + 4 * i) * B_DIM + b) * E_DIM + h * HD + lane] = acc[i];
    }
}

// ---------------------------------------------------------------------------
extern "C" void kernel_launch(void* const* d_in, const int* in_sizes, int n_in,
                              void* d_out, int out_size, void* d_ws, size_t ws_size,
                              hipStream_t stream)
{
    const float* x     = (const float*)d_in[0];
    const float* w_in  = (const float*)d_in[1];
    const float* b_in  = (const float*)d_in[2];
    const float* w_out = (const float*)d_in[3];
    const float* b_out = (const float*)d_in[4];

    float* out = (float*)d_out;
    float* avg = out + (size_t)T_DIM * B_DIM * E_DIM;

    float* ws = (float*)d_ws;
    const size_t HSZ = (size_t)B_DIM * H_DIM * T_DIM * HD;  // 4M floats
    float* qb  = ws;
    float* kb  = qb + HSZ;
    float* vb  = kb + HSZ;
    float* ctx = vb + HSZ;

    // avg region is accumulated via atomics -> zero it first
    hipMemsetAsync(avg, 0, (size_t)B_DIM * T_DIM * T_DIM * sizeof(float), stream);

    // QKV projection
    gemm_nt<0><<<dim3(F_DIM / 64, M_DIM / 64), 256, 0, stream>>>(
        x, w_in, b_in, qb, kb, vb, nullptr);

    // attention
    attn_kernel<<<dim3(T_DIM / 32, B_DIM * H_DIM), 256, 0, stream>>>(
        qb, kb, vb, ctx, avg);

    // output projection
    gemm_nt<1><<<dim3(E_DIM / 64, M_DIM / 64), 256, 0, stream>>>(
        ctx, w_out, b_out, nullptr, nullptr, nullptr, out);
}

// Round 3
// 728.432 us; speedup vs baseline: 4.0751x; 4.0751x over previous
//
#include <hip/hip_runtime.h>

// MultiheadAttn fwd. T=2048, B=2, E=1024, H=16, hd=64.
// Pipeline: gemm_nt<0> (fp32 GEMM -> bf16 q*scale,k,v) -> flash_kernel (MFMA bf16,
// single-pass online softmax, ctx fp32 + (m,1/l) to ws) -> avg_kernel (MFMA bf16
// score recompute over all heads, atomic-free avg write) -> gemm_nt<1> (fp32 out-proj).

#define T_DIM 2048
#define B_DIM 2
#define E_DIM 1024
#define H_DIM 16
#define HD 64
#define F_DIM 3072
#define M_DIM (T_DIM * B_DIM)
#define SCALE 0.125f

typedef __attribute__((ext_vector_type(8))) short bf16x8;
typedef __attribute__((ext_vector_type(4))) float f32x4;

__device__ inline unsigned short f2bf(float f) {
    union { float f; unsigned u; } v; v.f = f;
    unsigned r = v.u + 0x7fff + ((v.u >> 16) & 1);   // RNE
    return (unsigned short)(r >> 16);
}

// ---------------------------------------------------------------------------
// fp32 GEMM (NT): C[r,f] = sum_e A[r,e]*W[f,e] + bias[f]
// MODE 0: store bf16 into q(,*SCALE)/k/v head-major [n=b*H+h][t][d].
// MODE 1: store fp32 out[r*E+f].
// ---------------------------------------------------------------------------
template <int MODE>
__global__ __launch_bounds__(256) void gemm_nt(
    const float* __restrict__ A, const float* __restrict__ W,
    const float* __restrict__ bias,
    unsigned short* __restrict__ qb, unsigned short* __restrict__ kb,
    unsigned short* __restrict__ vb, float* __restrict__ outp)
{
    __shared__ float As[16][68];
    __shared__ float Bs[16][68];

    const int tid = threadIdx.x;
    const int tx = tid & 15, ty = tid >> 4;
    const int n0 = blockIdx.x * 64, m0 = blockIdx.y * 64;
    const int lrow = tid >> 2, lc4 = tid & 3;

    float acc[4][4] = {};

    for (int k0 = 0; k0 < E_DIM; k0 += 16) {
        __syncthreads();
        float4 av = *(const float4*)&A[(size_t)(m0 + lrow) * E_DIM + k0 + lc4 * 4];
        float4 bv = *(const float4*)&W[(size_t)(n0 + lrow) * E_DIM + k0 + lc4 * 4];
        As[lc4 * 4 + 0][lrow] = av.x; As[lc4 * 4 + 1][lrow] = av.y;
        As[lc4 * 4 + 2][lrow] = av.z; As[lc4 * 4 + 3][lrow] = av.w;
        Bs[lc4 * 4 + 0][lrow] = bv.x; Bs[lc4 * 4 + 1][lrow] = bv.y;
        Bs[lc4 * 4 + 2][lrow] = bv.z; Bs[lc4 * 4 + 3][lrow] = bv.w;
        __syncthreads();
#pragma unroll
        for (int kk = 0; kk < 16; ++kk) {
            float4 a4 = *(const float4*)&As[kk][ty * 4];
            float4 b4 = *(const float4*)&Bs[kk][tx * 4];
            float am[4] = {a4.x, a4.y, a4.z, a4.w};
            float bn[4] = {b4.x, b4.y, b4.z, b4.w};
#pragma unroll
            for (int i = 0; i < 4; ++i)
#pragma unroll
                for (int j = 0; j < 4; ++j)
                    acc[i][j] += am[i] * bn[j];
        }
    }

#pragma unroll
    for (int i = 0; i < 4; ++i) {
        const int r = m0 + ty * 4 + i;
        const int t = r >> 1, b = r & 1;
#pragma unroll
        for (int j = 0; j < 4; ++j) {
            const int f = n0 + tx * 4 + j;
            float val = acc[i][j] + bias[f];
            if (MODE == 0) {
                const int sec = f >> 10;
                const int rem = f & 1023;
                const int h = rem >> 6, d = rem & 63;
                const size_t idx = ((size_t)(b * H_DIM + h) * T_DIM + t) * HD + d;
                if (sec == 0)      qb[idx] = f2bf(val * SCALE);
                else if (sec == 1) kb[idx] = f2bf(val);
                else               vb[idx] = f2bf(val);
            } else {
                outp[(size_t)r * E_DIM + f] = val;
            }
        }
    }
}

// ---------------------------------------------------------------------------
// Flash attention, bf16 MFMA. Block = (q-tile 64, head n). 4 waves, wave w
// owns q rows w*16..w*16+15. Single pass over K/V tiles of 64, online softmax.
// Writes ctx fp32 [t,b,e] and (m, 1/l) per q-row.
// ---------------------------------------------------------------------------
__global__ __launch_bounds__(256) void flash_kernel(
    const unsigned short* __restrict__ qb, const unsigned short* __restrict__ kb,
    const unsigned short* __restrict__ vb, float* __restrict__ ctxbuf,
    float2* __restrict__ ml)
{
    __shared__ short Ks[64][72];   // [key][d]   stride 144B: b128-aligned, ~2-way banks
    __shared__ short Vt[64][72];   // [d][key]
    __shared__ short Ps[64][72];   // [q][key]   per-wave 16-row stripes

    const int tid  = threadIdx.x;
    const int lane = tid & 63;
    const int w    = tid >> 6;
    const int l16  = lane & 15;
    const int g    = lane >> 4;          // 16-lane group 0..3
    const int q0   = blockIdx.x * 64;
    const int n    = blockIdx.y;         // b*H+h
    const int b    = n >> 4, h = n & 15;

    // staging maps
    const int krow = tid >> 2, kd0 = (tid & 3) << 4;   // K: coalesced 128B lines
    const int vrow = tid & 63, vd0 = (tid >> 6) << 4;  // V: conflict-free transpose writes

    // Q fragments held in registers for the whole block (A-frag: row=l16, k=g*8+e)
    const size_t qrow = (size_t)n * T_DIM + q0 + w * 16 + l16;
    bf16x8 qf0 = *(const bf16x8*)&qb[qrow * HD + g * 8];
    bf16x8 qf1 = *(const bf16x8*)&qb[qrow * HD + 32 + g * 8];

    f32x4 ctx[4] = {};         // [dtile]; D-layout: row q = w*16+g*4+reg, col d = dtile*16+l16
    float m_[4], l_[4];
#pragma unroll
    for (int r = 0; r < 4; ++r) { m_[r] = -1e30f; l_[r] = 0.f; }

    for (int kt = 0; kt < T_DIM; kt += 64) {
        __syncthreads();
        // stage K tile
        const size_t kgrow = (size_t)n * T_DIM + kt;
        *(bf16x8*)&Ks[krow][kd0]     = *(const bf16x8*)&kb[(kgrow + krow) * HD + kd0];
        *(bf16x8*)&Ks[krow][kd0 + 8] = *(const bf16x8*)&kb[(kgrow + krow) * HD + kd0 + 8];
        // stage V transposed
        bf16x8 v0 = *(const bf16x8*)&vb[(kgrow + vrow) * HD + vd0];
        bf16x8 v1 = *(const bf16x8*)&vb[(kgrow + vrow) * HD + vd0 + 8];
#pragma unroll
        for (int e = 0; e < 8; ++e) {
            Vt[vd0 + e][vrow]     = v0[e];
            Vt[vd0 + 8 + e][vrow] = v1[e];
        }
        __syncthreads();

        // S = Q*K^T : 4 ntiles of 16 keys
        f32x4 s[4];
#pragma unroll
        for (int nt = 0; nt < 4; ++nt) {
            bf16x8 kf0 = *(const bf16x8*)&Ks[nt * 16 + l16][g * 8];
            bf16x8 kf1 = *(const bf16x8*)&Ks[nt * 16 + l16][32 + g * 8];
            f32x4 z = {0.f, 0.f, 0.f, 0.f};
            z = __builtin_amdgcn_mfma_f32_16x16x32_bf16(qf0, kf0, z, 0, 0, 0);
            z = __builtin_amdgcn_mfma_f32_16x16x32_bf16(qf1, kf1, z, 0, 0, 0);
            s[nt] = z;
        }

        // online softmax per q-row (lane owns rows g*4+r; keys spread over l16 x nt)
        float p[4][4];
#pragma unroll
        for (int r = 0; r < 4; ++r) {
            float mt = fmaxf(fmaxf(s[0][r], s[1][r]), fmaxf(s[2][r], s[3][r]));
            mt = fmaxf(mt, __shfl_xor(mt, 1));
            mt = fmaxf(mt, __shfl_xor(mt, 2));
            mt = fmaxf(mt, __shfl_xor(mt, 4));
            mt = fmaxf(mt, __shfl_xor(mt, 8));
            float mnew = fmaxf(m_[r], mt);
            float f = __expf(m_[r] - mnew);
            float rs = 0.f;
#pragma unroll
            for (int nt = 0; nt < 4; ++nt) { p[nt][r] = __expf(s[nt][r] - mnew); rs += p[nt][r]; }
            rs += __shfl_xor(rs, 1);
            rs += __shfl_xor(rs, 2);
            rs += __shfl_xor(rs, 4);
            rs += __shfl_xor(rs, 8);
            l_[r] = l_[r] * f + rs;
            m_[r] = mnew;
#pragma unroll
            for (int dt = 0; dt < 4; ++dt) ctx[dt][r] *= f;
        }

        // P -> LDS bf16 (own wave's stripe)
#pragma unroll
        for (int nt = 0; nt < 4; ++nt)
#pragma unroll
            for (int r = 0; r < 4; ++r)
                Ps[w * 16 + g * 4 + r][nt * 16 + l16] = (short)f2bf(p[nt][r]);

        // ctx += P * V  (A from own Ps stripe, B from Vt)
        bf16x8 pa0 = *(const bf16x8*)&Ps[w * 16 + l16][g * 8];
        bf16x8 pa1 = *(const bf16x8*)&Ps[w * 16 + l16][32 + g * 8];
#pragma unroll
        for (int dt = 0; dt < 4; ++dt) {
            bf16x8 vf0 = *(const bf16x8*)&Vt[dt * 16 + l16][g * 8];
            bf16x8 vf1 = *(const bf16x8*)&Vt[dt * 16 + l16][32 + g * 8];
            ctx[dt] = __builtin_amdgcn_mfma_f32_16x16x32_bf16(pa0, vf0, ctx[dt], 0, 0, 0);
            ctx[dt] = __builtin_amdgcn_mfma_f32_16x16x32_bf16(pa1, vf1, ctx[dt], 0, 0, 0);
        }
    }

    float linv[4];
#pragma unroll
    for (int r = 0; r < 4; ++r) linv[r] = 1.0f / l_[r];

    // ctx store: [t, b, h*64+d]
#pragma unroll
    for (int dt = 0; dt < 4; ++dt)
#pragma unroll
        for (int r = 0; r < 4; ++r) {
            const int q = q0 + w * 16 + g * 4 + r;
            const int d = dt * 16 + l16;
            ctxbuf[((size_t)q * B_DIM + b) * E_DIM + h * HD + d] = ctx[dt][r] * linv[r];
        }

    if (l16 == 0) {
#pragma unroll
        for (int r = 0; r < 4; ++r)
            ml[(size_t)n * T_DIM + q0 + w * 16 + g * 4 + r] = make_float2(m_[r], linv[r]);
    }
}

// ---------------------------------------------------------------------------
// avg_weights: block = (kt-tile 64, q-tile 64, b). Recompute scores per head
// via MFMA, p = exp(s-m)*linv/H, accumulate over heads, write once. No atomics.
// ---------------------------------------------------------------------------
__global__ __launch_bounds__(256) void avg_kernel(
    const unsigned short* __restrict__ qb, const unsigned short* __restrict__ kb,
    const float2* __restrict__ ml, float* __restrict__ avg)
{
    __shared__ short Kh[64][72];

    const int tid  = threadIdx.x;
    const int lane = tid & 63;
    const int w    = tid >> 6;
    const int l16  = lane & 15;
    const int g    = lane >> 4;
    const int kt0  = blockIdx.x * 64;
    const int q0   = blockIdx.y * 64;
    const int b    = blockIdx.z;

    const int krow = tid >> 2, kd0 = (tid & 3) << 4;

    f32x4 acc[4] = {};   // [ntile]; D-layout rows q=w*16+g*4+reg, col key=ntile*16+l16

    for (int h = 0; h < H_DIM; ++h) {
        const int n = b * H_DIM + h;
        __syncthreads();
        const size_t kgrow = (size_t)n * T_DIM + kt0;
        *(bf16x8*)&Kh[krow][kd0]     = *(const bf16x8*)&kb[(kgrow + krow) * HD + kd0];
        *(bf16x8*)&Kh[krow][kd0 + 8] = *(const bf16x8*)&kb[(kgrow + krow) * HD + kd0 + 8];
        __syncthreads();

        const size_t qrow = (size_t)n * T_DIM + q0 + w * 16 + l16;
        bf16x8 qf0 = *(const bf16x8*)&qb[qrow * HD + g * 8];
        bf16x8 qf1 = *(const bf16x8*)&qb[qrow * HD + 32 + g * 8];

        float2 mlv[4];
#pragma unroll
        for (int r = 0; r < 4; ++r)
            mlv[r] = ml[(size_t)n * T_DIM + q0 + w * 16 + g * 4 + r];

#pragma unroll
        for (int nt = 0; nt < 4; ++nt) {
            bf16x8 kf0 = *(const bf16x8*)&Kh[nt * 16 + l16][g * 8];
            bf16x8 kf1 = *(const bf16x8*)&Kh[nt * 16 + l16][32 + g * 8];
            f32x4 z = {0.f, 0.f, 0.f, 0.f};
            z = __builtin_amdgcn_mfma_f32_16x16x32_bf16(qf0, kf0, z, 0, 0, 0);
            z = __builtin_amdgcn_mfma_f32_16x16x32_bf16(qf1, kf1, z, 0, 0, 0);
#pragma unroll
            for (int r = 0; r < 4; ++r)
                acc[nt][r] += __expf(z[r] - mlv[r].x) * mlv[r].y * (1.0f / H_DIM);
        }
    }

#pragma unroll
    for (int nt = 0; nt < 4; ++nt)
#pragma unroll
        for (int r = 0; r < 4; ++r) {
            const int q = q0 + w * 16 + g * 4 + r;
            avg[((size_t)b * T_DIM + q) * T_DIM + kt0 + nt * 16 + l16] = acc[nt][r];
        }
}

// ---------------------------------------------------------------------------
extern "C" void kernel_launch(void* const* d_in, const int* in_sizes, int n_in,
                              void* d_out, int out_size, void* d_ws, size_t ws_size,
                              hipStream_t stream)
{
    const float* x     = (const float*)d_in[0];
    const float* w_in  = (const float*)d_in[1];
    const float* b_in  = (const float*)d_in[2];
    const float* w_out = (const float*)d_in[3];
    const float* b_out = (const float*)d_in[4];

    float* out = (float*)d_out;
    float* avg = out + (size_t)T_DIM * B_DIM * E_DIM;

    const size_t HSZ = (size_t)B_DIM * H_DIM * T_DIM * HD;  // 4M elems
    unsigned short* qb = (unsigned short*)d_ws;
    unsigned short* kb = qb + HSZ;
    unsigned short* vb = kb + HSZ;
    float* ctx = (float*)(vb + HSZ);
    float2* ml = (float2*)(ctx + (size_t)T_DIM * B_DIM * E_DIM);

    // 1. QKV projection (fp32 compute, bf16 stores)
    gemm_nt<0><<<dim3(F_DIM / 64, M_DIM / 64), 256, 0, stream>>>(
        x, w_in, b_in, qb, kb, vb, nullptr);

    // 2. flash attention (MFMA)
    flash_kernel<<<dim3(T_DIM / 64, B_DIM * H_DIM), 256, 0, stream>>>(
        qb, kb, vb, ctx, ml);

    // 3. avg weights (MFMA, atomic-free)
    avg_kernel<<<dim3(T_DIM / 64, T_DIM / 64, B_DIM), 256, 0, stream>>>(
        qb, kb, ml, avg);

    // 4. output projection (fp32)
    gemm_nt<1><<<dim3(E_DIM / 64, M_DIM / 64), 256, 0, stream>>>(
        ctx, w_out, b_out, nullptr, nullptr, nullptr, out);
}

// Round 13
// 328.548 us; speedup vs baseline: 9.0351x; 2.2171x over previous
//
#include <hip/hip_runtime.h>

// MultiheadAttn fwd. T=2048, B=2, E=1024, H=16, hd=64.
// cast(x,Win,Wout->bf16) -> gemm_bf16<0> (MFMA QKV proj -> bf16 q*scale,k,v)
// -> flash_kernel (MFMA, online softmax, bf16 ctx + (m,1/l))
// -> avg_kernel (MFMA score recompute, atomic-free avg)
// -> gemm_bf16<1> (MFMA out-proj, fp32 out).

#define T_DIM 2048
#define B_DIM 2
#define E_DIM 1024
#define H_DIM 16
#define HD 64
#define F_DIM 3072
#define M_DIM (T_DIM * B_DIM)
#define SCALE 0.125f

typedef __attribute__((ext_vector_type(8))) short bf16x8;
typedef __attribute__((ext_vector_type(4))) float f32x4;

__device__ inline unsigned short f2bf(float f) {
    union { float f; unsigned u; } v; v.f = f;
    unsigned r = v.u + 0x7fff + ((v.u >> 16) & 1);   // RNE
    return (unsigned short)(r >> 16);
}

// ---------------------------------------------------------------------------
// fp32 -> bf16 cast, 8 elems/thread
// ---------------------------------------------------------------------------
__global__ __launch_bounds__(256) void cast_bf16(
    const float* __restrict__ src, unsigned short* __restrict__ dst, int n8)
{
    int i = blockIdx.x * 256 + threadIdx.x;
    if (i >= n8) return;
    float4 a = *(const float4*)&src[i * 8];
    float4 b = *(const float4*)&src[i * 8 + 4];
    bf16x8 o;
    o[0] = f2bf(a.x); o[1] = f2bf(a.y); o[2] = f2bf(a.z); o[3] = f2bf(a.w);
    o[4] = f2bf(b.x); o[5] = f2bf(b.y); o[6] = f2bf(b.z); o[7] = f2bf(b.w);
    *(bf16x8*)&dst[i * 8] = o;
}

// ---------------------------------------------------------------------------
// bf16 MFMA GEMM (NT): C[r,f] = sum_e A[r,e]*W[f,e] + bias[f], K=1024.
// 128x128 tile, BK=64, 4 waves in 2x2, per-wave 64x64.
// MODE 0: scatter-store bf16 q(*SCALE)/k/v head-major. MODE 1: fp32 out.
// ---------------------------------------------------------------------------
template <int MODE>
__global__ __launch_bounds__(256) void gemm_bf16(
    const unsigned short* __restrict__ A, const unsigned short* __restrict__ W,
    const float* __restrict__ bias,
    unsigned short* __restrict__ qb, unsigned short* __restrict__ kb,
    unsigned short* __restrict__ vb, float* __restrict__ outp)
{
    __shared__ short As[128][72];   // 144B row stride: banks advance 4/row
    __shared__ short Bs[128][72];

    const int tid  = threadIdx.x;
    const int lane = tid & 63;
    const int wv   = tid >> 6;
    const int l16  = lane & 15;
    const int g    = lane >> 4;
    const int wr   = wv >> 1, wc = wv & 1;     // 2x2 wave grid
    const int n0   = blockIdx.x * 128, m0 = blockIdx.y * 128;

    const int srow = tid >> 2;                  // 0..63
    const int sc   = (tid & 3) * 16;            // 0,16,32,48

    f32x4 acc[4][4] = {};

    for (int k0 = 0; k0 < E_DIM; k0 += 64) {
        __syncthreads();
#pragma unroll
        for (int i = 0; i < 2; ++i) {
            const int row = srow + i * 64;
            const size_t ga = (size_t)(m0 + row) * E_DIM + k0 + sc;
            const size_t gb = (size_t)(n0 + row) * E_DIM + k0 + sc;
            *(bf16x8*)&As[row][sc]     = *(const bf16x8*)&A[ga];
            *(bf16x8*)&As[row][sc + 8] = *(const bf16x8*)&A[ga + 8];
            *(bf16x8*)&Bs[row][sc]     = *(const bf16x8*)&W[gb];
            *(bf16x8*)&Bs[row][sc + 8] = *(const bf16x8*)&W[gb + 8];
        }
        __syncthreads();

        bf16x8 af[4][2], bf[4][2];
#pragma unroll
        for (int mt = 0; mt < 4; ++mt) {
            af[mt][0] = *(const bf16x8*)&As[wr * 64 + mt * 16 + l16][g * 8];
            af[mt][1] = *(const bf16x8*)&As[wr * 64 + mt * 16 + l16][32 + g * 8];
        }
#pragma unroll
        for (int nt = 0; nt < 4; ++nt) {
            bf[nt][0] = *(const bf16x8*)&Bs[wc * 64 + nt * 16 + l16][g * 8];
            bf[nt][1] = *(const bf16x8*)&Bs[wc * 64 + nt * 16 + l16][32 + g * 8];
        }
#pragma unroll
        for (int mt = 0; mt < 4; ++mt)
#pragma unroll
            for (int nt = 0; nt < 4; ++nt) {
                acc[mt][nt] = __builtin_amdgcn_mfma_f32_16x16x32_bf16(
                    af[mt][0], bf[nt][0], acc[mt][nt], 0, 0, 0);
                acc[mt][nt] = __builtin_amdgcn_mfma_f32_16x16x32_bf16(
                    af[mt][1], bf[nt][1], acc[mt][nt], 0, 0, 0);
            }
    }

#pragma unroll
    for (int mt = 0; mt < 4; ++mt)
#pragma unroll
        for (int nt = 0; nt < 4; ++nt)
#pragma unroll
            for (int rr = 0; rr < 4; ++rr) {
                const int r = m0 + wr * 64 + mt * 16 + g * 4 + rr;
                const int f = n0 + wc * 64 + nt * 16 + l16;
                float val = acc[mt][nt][rr] + bias[f];
                if (MODE == 0) {
                    const int t = r >> 1, b = r & 1;
                    const int sec = f >> 10, rem = f & 1023;
                    const int h = rem >> 6, d = rem & 63;
                    const size_t idx = ((size_t)(b * H_DIM + h) * T_DIM + t) * HD + d;
                    if (sec == 0)      qb[idx] = f2bf(val * SCALE);
                    else if (sec == 1) kb[idx] = f2bf(val);
                    else               vb[idx] = f2bf(val);
                } else {
                    outp[(size_t)r * E_DIM + f] = val;
                }
            }
}

// ---------------------------------------------------------------------------
// Flash attention, bf16 MFMA. Block = (q-tile 64, head n). ctx stored bf16.
// ---------------------------------------------------------------------------
__global__ __launch_bounds__(256) void flash_kernel(
    const unsigned short* __restrict__ qb, const unsigned short* __restrict__ kb,
    const unsigned short* __restrict__ vb, unsigned short* __restrict__ ctxbuf,
    float2* __restrict__ ml)
{
    __shared__ short Ks[64][72];
    __shared__ short Vt[64][72];
    __shared__ short Ps[64][72];

    const int tid  = threadIdx.x;
    const int lane = tid & 63;
    const int w    = tid >> 6;
    const int l16  = lane & 15;
    const int g    = lane >> 4;
    const int q0   = blockIdx.x * 64;
    const int n    = blockIdx.y;
    const int b    = n >> 4, h = n & 15;

    const int krow = tid >> 2, kd0 = (tid & 3) << 4;
    const int vrow = tid & 63, vd0 = (tid >> 6) << 4;

    const size_t qrow = (size_t)n * T_DIM + q0 + w * 16 + l16;
    bf16x8 qf0 = *(const bf16x8*)&qb[qrow * HD + g * 8];
    bf16x8 qf1 = *(const bf16x8*)&qb[qrow * HD + 32 + g * 8];

    f32x4 ctx[4] = {};
    float m_[4], l_[4];
#pragma unroll
    for (int r = 0; r < 4; ++r) { m_[r] = -1e30f; l_[r] = 0.f; }

    for (int kt = 0; kt < T_DIM; kt += 64) {
        __syncthreads();
        const size_t kgrow = (size_t)n * T_DIM + kt;
        *(bf16x8*)&Ks[krow][kd0]     = *(const bf16x8*)&kb[(kgrow + krow) * HD + kd0];
        *(bf16x8*)&Ks[krow][kd0 + 8] = *(const bf16x8*)&kb[(kgrow + krow) * HD + kd0 + 8];
        bf16x8 v0 = *(const bf16x8*)&vb[(kgrow + vrow) * HD + vd0];
        bf16x8 v1 = *(const bf16x8*)&vb[(kgrow + vrow) * HD + vd0 + 8];
#pragma unroll
        for (int e = 0; e < 8; ++e) {
            Vt[vd0 + e][vrow]     = v0[e];
            Vt[vd0 + 8 + e][vrow] = v1[e];
        }
        __syncthreads();

        f32x4 s[4];
#pragma unroll
        for (int nt = 0; nt < 4; ++nt) {
            bf16x8 kf0 = *(const bf16x8*)&Ks[nt * 16 + l16][g * 8];
            bf16x8 kf1 = *(const bf16x8*)&Ks[nt * 16 + l16][32 + g * 8];
            f32x4 z = {0.f, 0.f, 0.f, 0.f};
            z = __builtin_amdgcn_mfma_f32_16x16x32_bf16(qf0, kf0, z, 0, 0, 0);
            z = __builtin_amdgcn_mfma_f32_16x16x32_bf16(qf1, kf1, z, 0, 0, 0);
            s[nt] = z;
        }

        float p[4][4];
#pragma unroll
        for (int r = 0; r < 4; ++r) {
            float mt = fmaxf(fmaxf(s[0][r], s[1][r]), fmaxf(s[2][r], s[3][r]));
            mt = fmaxf(mt, __shfl_xor(mt, 1));
            mt = fmaxf(mt, __shfl_xor(mt, 2));
            mt = fmaxf(mt, __shfl_xor(mt, 4));
            mt = fmaxf(mt, __shfl_xor(mt, 8));
            float mnew = fmaxf(m_[r], mt);
            float f = __expf(m_[r] - mnew);
            float rs = 0.f;
#pragma unroll
            for (int nt = 0; nt < 4; ++nt) { p[nt][r] = __expf(s[nt][r] - mnew); rs += p[nt][r]; }
            rs += __shfl_xor(rs, 1);
            rs += __shfl_xor(rs, 2);
            rs += __shfl_xor(rs, 4);
            rs += __shfl_xor(rs, 8);
            l_[r] = l_[r] * f + rs;
            m_[r] = mnew;
#pragma unroll
            for (int dt = 0; dt < 4; ++dt) ctx[dt][r] *= f;
        }

#pragma unroll
        for (int nt = 0; nt < 4; ++nt)
#pragma unroll
            for (int r = 0; r < 4; ++r)
                Ps[w * 16 + g * 4 + r][nt * 16 + l16] = (short)f2bf(p[nt][r]);

        bf16x8 pa0 = *(const bf16x8*)&Ps[w * 16 + l16][g * 8];
        bf16x8 pa1 = *(const bf16x8*)&Ps[w * 16 + l16][32 + g * 8];
#pragma unroll
        for (int dt = 0; dt < 4; ++dt) {
            bf16x8 vf0 = *(const bf16x8*)&Vt[dt * 16 + l16][g * 8];
            bf16x8 vf1 = *(const bf16x8*)&Vt[dt * 16 + l16][32 + g * 8];
            ctx[dt] = __builtin_amdgcn_mfma_f32_16x16x32_bf16(pa0, vf0, ctx[dt], 0, 0, 0);
            ctx[dt] = __builtin_amdgcn_mfma_f32_16x16x32_bf16(pa1, vf1, ctx[dt], 0, 0, 0);
        }
    }

    float linv[4];
#pragma unroll
    for (int r = 0; r < 4; ++r) linv[r] = 1.0f / l_[r];

#pragma unroll
    for (int dt = 0; dt < 4; ++dt)
#pragma unroll
        for (int r = 0; r < 4; ++r) {
            const int q = q0 + w * 16 + g * 4 + r;
            const int d = dt * 16 + l16;
            ctxbuf[((size_t)q * B_DIM + b) * E_DIM + h * HD + d] = f2bf(ctx[dt][r] * linv[r]);
        }

    if (l16 == 0) {
#pragma unroll
        for (int r = 0; r < 4; ++r)
            ml[(size_t)n * T_DIM + q0 + w * 16 + g * 4 + r] = make_float2(m_[r], linv[r]);
    }
}

// ---------------------------------------------------------------------------
// avg_weights: block = (kt-tile 64, q-tile 64, b). MFMA recompute, no atomics.
// ---------------------------------------------------------------------------
__global__ __launch_bounds__(256) void avg_kernel(
    const unsigned short* __restrict__ qb, const unsigned short* __restrict__ kb,
    const float2* __restrict__ ml, float* __restrict__ avg)
{
    __shared__ short Kh[64][72];

    const int tid  = threadIdx.x;
    const int lane = tid & 63;
    const int w    = tid >> 6;
    const int l16  = lane & 15;
    const int g    = lane >> 4;
    const int kt0  = blockIdx.x * 64;
    const int q0   = blockIdx.y * 64;
    const int b    = blockIdx.z;

    const int krow = tid >> 2, kd0 = (tid & 3) << 4;

    f32x4 acc[4] = {};

    for (int h = 0; h < H_DIM; ++h) {
        const int n = b * H_DIM + h;
        __syncthreads();
        const size_t kgrow = (size_t)n * T_DIM + kt0;
        *(bf16x8*)&Kh[krow][kd0]     = *(const bf16x8*)&kb[(kgrow + krow) * HD + kd0];
        *(bf16x8*)&Kh[krow][kd0 + 8] = *(const bf16x8*)&kb[(kgrow + krow) * HD + kd0 + 8];
        __syncthreads();

        const size_t qrow = (size_t)n * T_DIM + q0 + w * 16 + l16;
        bf16x8 qf0 = *(const bf16x8*)&qb[qrow * HD + g * 8];
        bf16x8 qf1 = *(const bf16x8*)&qb[qrow * HD + 32 + g * 8];

        float2 mlv[4];
#pragma unroll
        for (int r = 0; r < 4; ++r)
            mlv[r] = ml[(size_t)n * T_DIM + q0 + w * 16 + g * 4 + r];

#pragma unroll
        for (int nt = 0; nt < 4; ++nt) {
            bf16x8 kf0 = *(const bf16x8*)&Kh[nt * 16 + l16][g * 8];
            bf16x8 kf1 = *(const bf16x8*)&Kh[nt * 16 + l16][32 + g * 8];
            f32x4 z = {0.f, 0.f, 0.f, 0.f};
            z = __builtin_amdgcn_mfma_f32_16x16x32_bf16(qf0, kf0, z, 0, 0, 0);
            z = __builtin_amdgcn_mfma_f32_16x16x32_bf16(qf1, kf1, z, 0, 0, 0);
#pragma unroll
            for (int r = 0; r < 4; ++r)
                acc[nt][r] += __expf(z[r] - mlv[r].x) * mlv[r].y * (1.0f / H_DIM);
        }
    }

#pragma unroll
    for (int nt = 0; nt < 4; ++nt)
#pragma unroll
        for (int r = 0; r < 4; ++r) {
            const int q = q0 + w * 16 + g * 4 + r;
            avg[((size_t)b * T_DIM + q) * T_DIM + kt0 + nt * 16 + l16] = acc[nt][r];
        }
}

// ---------------------------------------------------------------------------
extern "C" void kernel_launch(void* const* d_in, const int* in_sizes, int n_in,
                              void* d_out, int out_size, void* d_ws, size_t ws_size,
                              hipStream_t stream)
{
    const float* x     = (const float*)d_in[0];
    const float* w_in  = (const float*)d_in[1];
    const float* b_in  = (const float*)d_in[2];
    const float* w_out = (const float*)d_in[3];
    const float* b_out = (const float*)d_in[4];

    float* out = (float*)d_out;
    float* avg = out + (size_t)T_DIM * B_DIM * E_DIM;

    const size_t HSZ = (size_t)B_DIM * H_DIM * T_DIM * HD;     // 4M elems
    unsigned short* qb   = (unsigned short*)d_ws;
    unsigned short* kb   = qb + HSZ;
    unsigned short* vb   = kb + HSZ;
    unsigned short* ctxb = vb + HSZ;                            // [T,B,E] bf16
    unsigned short* xb   = ctxb + (size_t)T_DIM * B_DIM * E_DIM;
    unsigned short* wbin = xb + (size_t)T_DIM * B_DIM * E_DIM;  // [3E,E]
    unsigned short* wbot = wbin + (size_t)F_DIM * E_DIM;        // [E,E]
    float2* ml = (float2*)(wbot + (size_t)E_DIM * E_DIM);

    // 0. casts
    cast_bf16<<<(T_DIM * B_DIM * E_DIM / 8 + 255) / 256, 256, 0, stream>>>(
        x, xb, T_DIM * B_DIM * E_DIM / 8);
    cast_bf16<<<(F_DIM * E_DIM / 8 + 255) / 256, 256, 0, stream>>>(
        w_in, wbin, F_DIM * E_DIM / 8);
    cast_bf16<<<(E_DIM * E_DIM / 8 + 255) / 256, 256, 0, stream>>>(
        w_out, wbot, E_DIM * E_DIM / 8);

    // 1. QKV projection (MFMA bf16)
    gemm_bf16<0><<<dim3(F_DIM / 128, M_DIM / 128), 256, 0, stream>>>(
        xb, wbin, b_in, qb, kb, vb, nullptr);

    // 2. flash attention
    flash_kernel<<<dim3(T_DIM / 64, B_DIM * H_DIM), 256, 0, stream>>>(
        qb, kb, vb, ctxb, ml);

    // 3. avg weights
    avg_kernel<<<dim3(T_DIM / 64, T_DIM / 64, B_DIM), 256, 0, stream>>>(
        qb, kb, ml, avg);

    // 4. output projection (MFMA bf16 -> fp32)
    gemm_bf16<1><<<dim3(E_DIM / 128, M_DIM / 128), 256, 0, stream>>>(
        ctxb, wbot, b_out, nullptr, nullptr, nullptr, out);
}